// Round 1
// baseline (13392.839 us; speedup 1.0000x reference)
//
#include <hip/hip_runtime.h>
#include <hip/hip_bf16.h>

// Problem constants (from reference): B=512 T=512 I=128 H=512 C=128 OUT_T=128
#define Bq 512
#define Tq 512
#define Iq 128
#define Hq 512
#define Cq 128
#define OUT_Tq 128
#define Gq 4   // batches per block

// ---- workspace layout (float offsets) ----
// wt_enc : [160][512][4]  (k=0..639 transposed; k<128 from W_ih, else W_hh)   327680 floats
// wt_fc1 : [128][512][4]                                                      262144 floats
// wt_fc2 : [128][128][4]                                                       65536 floats
// cbias  : [512]  (b_ih + b_hh)                                                 512 floats
#define OFF_WTENC 0
#define OFF_WTFC1 327680
#define OFF_WTFC2 589824
#define OFF_CBIAS 655360

__global__ void prep_enc(const float* __restrict__ W_ih, const float* __restrict__ W_hh,
                         float* __restrict__ wt) {
    int idx = blockIdx.x * 256 + threadIdx.x;           // over 512*640
    if (idx >= 512 * 640) return;
    int n = idx / 640, k = idx % 640;
    float v = (k < Iq) ? W_ih[n * Iq + k] : W_hh[n * Hq + (k - Iq)];
    wt[(k >> 2) * 2048 + n * 4 + (k & 3)] = v;
}

__global__ void prep_fc1(const float* __restrict__ W, float* __restrict__ wt) {
    int idx = blockIdx.x * 256 + threadIdx.x;           // over 512*512
    if (idx >= 512 * 512) return;
    int n = idx >> 9, k = idx & 511;
    wt[(k >> 2) * 2048 + n * 4 + (k & 3)] = W[n * Hq + k];
}

__global__ void prep_fc2(const float* __restrict__ W, float* __restrict__ wt) {
    int idx = blockIdx.x * 256 + threadIdx.x;           // over 128*512
    if (idx >= 128 * 512) return;
    int c = idx >> 9, k = idx & 511;
    wt[(k >> 2) * 512 + c * 4 + (k & 3)] = W[c * Hq + k];
}

__global__ void prep_bias(const float* __restrict__ bih, const float* __restrict__ bhh,
                          float* __restrict__ cb) {
    int n = blockIdx.x * 256 + threadIdx.x;
    if (n < Hq) cb[n] = bih[n] + bhh[n];
}

__device__ __forceinline__ float dot4(float4 w, float4 v) {
    return w.x * v.x + w.y * v.y + w.z * v.z + w.w * v.w;
}

__global__ void __launch_bounds__(512)
rnn_fused(const float* __restrict__ x, const int* __restrict__ lengths,
          const float* __restrict__ wt_enc, const float* __restrict__ wt_fc1,
          const float* __restrict__ wt_fc2, const float* __restrict__ cbias,
          const float* __restrict__ fc1_b, const float* __restrict__ fc2_b,
          float* __restrict__ out) {
    __shared__ __align__(16) float in_s[Gq][Iq + Hq];   // [x_t | h]
    __shared__ __align__(16) float mid_s[Gq][Hq];

    const int tid = threadIdx.x;          // 0..511
    const int n = tid;
    const int gb0 = blockIdx.x * Gq;

    const int len0 = lengths[gb0 + 0];
    const int len1 = lengths[gb0 + 1];
    const int len2 = lengths[gb0 + 2];
    const int len3 = lengths[gb0 + 3];
    int tmax = max(max(len0, len1), max(len2, len3));

    // h = 0
    for (int b = 0; b < Gq; ++b) in_s[b][Iq + tid] = 0.f;
    __syncthreads();

    const float4* We = (const float4*)wt_enc;           // [160][512]
    const float cb = cbias[n];

    // ---------------- encoder ----------------
    for (int t = 0; t < tmax; ++t) {
        {   // stage x_t for the 4 batches (coalesced: 4 x 512B segments)
            int b = tid >> 7, i = tid & 127;
            in_s[b][i] = x[(size_t)(gb0 + b) * Tq * Iq + (size_t)t * Iq + i];
        }
        __syncthreads();
        float a0 = 0.f, a1 = 0.f, a2 = 0.f, a3 = 0.f;
#pragma unroll 4
        for (int k0 = 0; k0 < 160; ++k0) {
            float4 w = We[k0 * 512 + n];                 // coalesced dwordx4
            float4 i0 = *(const float4*)&in_s[0][k0 * 4];  // LDS broadcast
            float4 i1 = *(const float4*)&in_s[1][k0 * 4];
            float4 i2 = *(const float4*)&in_s[2][k0 * 4];
            float4 i3 = *(const float4*)&in_s[3][k0 * 4];
            a0 += dot4(w, i0); a1 += dot4(w, i1);
            a2 += dot4(w, i2); a3 += dot4(w, i3);
        }
        float nh0 = tanhf(a0 + cb);
        float nh1 = tanhf(a1 + cb);
        float nh2 = tanhf(a2 + cb);
        float nh3 = tanhf(a3 + cb);
        __syncthreads();    // all reads of in_s done
        if (t < len0) in_s[0][Iq + n] = nh0;
        if (t < len1) in_s[1][Iq + n] = nh1;
        if (t < len2) in_s[2][Iq + n] = nh2;
        if (t < len3) in_s[3][Iq + n] = nh3;
        // next iter: x-stage writes disjoint region; sync there publishes h
    }
    __syncthreads();

    // ---------------- decoder ----------------
    const float4* Wd = We + 32 * 512;                   // W_hh^T rows (k0 = 0..127)
    const float4* W1 = (const float4*)wt_fc1;
    const float4* W2 = (const float4*)wt_fc2;
    const float f1b = fc1_b[n];
    const int bq = tid >> 7, c = tid & 127;
    const float f2b = fc2_b[c];

    for (int t = 0; t < OUT_Tq; ++t) {
        // nh = tanh(cbias + h @ W_hh^T)
        float a0 = 0.f, a1 = 0.f, a2 = 0.f, a3 = 0.f;
#pragma unroll 4
        for (int k0 = 0; k0 < 128; ++k0) {
            float4 w = Wd[k0 * 512 + n];
            float4 h0 = *(const float4*)&in_s[0][Iq + k0 * 4];
            float4 h1 = *(const float4*)&in_s[1][Iq + k0 * 4];
            float4 h2 = *(const float4*)&in_s[2][Iq + k0 * 4];
            float4 h3 = *(const float4*)&in_s[3][Iq + k0 * 4];
            a0 += dot4(w, h0); a1 += dot4(w, h1);
            a2 += dot4(w, h2); a3 += dot4(w, h3);
        }
        float nh0 = tanhf(a0 + cb);
        float nh1 = tanhf(a1 + cb);
        float nh2 = tanhf(a2 + cb);
        float nh3 = tanhf(a3 + cb);
        __syncthreads();
        in_s[0][Iq + n] = nh0;
        in_s[1][Iq + n] = nh1;
        in_s[2][Iq + n] = nh2;
        in_s[3][Iq + n] = nh3;
        __syncthreads();
        // mid = relu(nh @ fc1^T + fc1_b)
        a0 = a1 = a2 = a3 = 0.f;
#pragma unroll 4
        for (int k0 = 0; k0 < 128; ++k0) {
            float4 w = W1[k0 * 512 + n];
            float4 h0 = *(const float4*)&in_s[0][Iq + k0 * 4];
            float4 h1 = *(const float4*)&in_s[1][Iq + k0 * 4];
            float4 h2 = *(const float4*)&in_s[2][Iq + k0 * 4];
            float4 h3 = *(const float4*)&in_s[3][Iq + k0 * 4];
            a0 += dot4(w, h0); a1 += dot4(w, h1);
            a2 += dot4(w, h2); a3 += dot4(w, h3);
        }
        mid_s[0][n] = fmaxf(a0 + f1b, 0.f);
        mid_s[1][n] = fmaxf(a1 + f1b, 0.f);
        mid_s[2][n] = fmaxf(a2 + f1b, 0.f);
        mid_s[3][n] = fmaxf(a3 + f1b, 0.f);
        __syncthreads();
        // out = mid @ fc2^T + fc2_b   (thread -> (bq, c))
        float ao = 0.f;
#pragma unroll 4
        for (int k0 = 0; k0 < 128; ++k0) {
            float4 w = W2[k0 * 128 + c];
            float4 m = *(const float4*)&mid_s[bq][k0 * 4];
            ao += dot4(w, m);
        }
        out[((size_t)(gb0 + bq) * OUT_Tq + t) * Cq + c] = ao + f2b;
        __syncthreads();    // mid reads done before next-iter writes
    }
}

extern "C" void kernel_launch(void* const* d_in, const int* in_sizes, int n_in,
                              void* d_out, int out_size, void* d_ws, size_t ws_size,
                              hipStream_t stream) {
    const float* x      = (const float*)d_in[0];
    const int*   lens   = (const int*)d_in[1];
    // d_in[2] = out_lengths (constant 128, hardcoded)
    const float* W_ih   = (const float*)d_in[3];
    const float* W_hh   = (const float*)d_in[4];
    const float* b_ih   = (const float*)d_in[5];
    const float* b_hh   = (const float*)d_in[6];
    const float* fc1_W  = (const float*)d_in[7];
    const float* fc1_b  = (const float*)d_in[8];
    const float* fc2_W  = (const float*)d_in[9];
    const float* fc2_b  = (const float*)d_in[10];

    float* ws   = (float*)d_ws;
    float* wtE  = ws + OFF_WTENC;
    float* wt1  = ws + OFF_WTFC1;
    float* wt2  = ws + OFF_WTFC2;
    float* cb   = ws + OFF_CBIAS;

    prep_enc <<<1280, 256, 0, stream>>>(W_ih, W_hh, wtE);
    prep_fc1 <<<1024, 256, 0, stream>>>(fc1_W, wt1);
    prep_fc2 <<< 256, 256, 0, stream>>>(fc2_W, wt2);
    prep_bias<<<   2, 256, 0, stream>>>(b_ih, b_hh, cb);

    rnn_fused<<<Bq / Gq, 512, 0, stream>>>(x, lens, wtE, wt1, wt2, cb,
                                           fc1_b, fc2_b, (float*)d_out);
}